// Round 3
// baseline (248.715 us; speedup 1.0000x reference)
//
#include <hip/hip_runtime.h>

#define K0 3072
#define BPB 32            // batch rows per block
#define BLOCK 1024        // 16 waves: wave = (r<<3) | chunk
#define ROWS 2            // rows interleaved for ILP

struct KtreeArgs {
  const float* x;
  const float* ap1; const float* ap2; const float* am1; const float* am2; const float* g0;
  const float* w[11];
  const float* bs[11];
  const float* root_w; const float* root_b;
  float* out;
};

__device__ __forceinline__ float lrelu(float v) {
  return v >= 0.0f ? v : 0.01f * v;
}

__global__ __launch_bounds__(BLOCK, 4) void ktree_synapse_kernel(KtreeArgs A) {
  const int tid = threadIdx.x;
  const int wv  = tid >> 6;        // 0..15
  const int l   = tid & 63;
  const int c   = wv & 7;          // k-chunk: K=8-level node index
  const int r   = wv >> 3;         // population 0/1

  // natural order: lane l owns K=512-level node c*64 + l (coalesced x reads)
  const int node512 = c * 64 + l;
  const int kb      = node512 * 6;

  const float LOG2E = 1.4426950408889634f;
  const float CL    = 60.0f * 1.4426950408889634f;   // clip bound in log2 space

  // ---- persistent per-lane params (registers, constant across rows) ----
  float p1l[6], p2l[6], m1l[6], m2l[6], z0v[6], z65[6];
  {
    const int o = r * K0 + kb;
    #pragma unroll
    for (int j = 0; j < 6; ++j) {
      p1l[j] = A.ap1[o + j] * LOG2E;
      p2l[j] = A.ap2[o + j] * LOG2E;
      m1l[j] = A.am1[o + j] * LOG2E;
      m2l[j] = A.am2[o + j] * LOG2E;
      z0v[j] = A.g0[o + j];
      z65[j] = -65.0f * z0v[j];
    }
  }
  // level 0 (3072->1024, f=3): lane owns K=1024 nodes 2*node512, 2*node512+1
  float w0v[6], b0a, b0b;
  {
    const int o = (r * 1024 + 2 * node512) * 3;
    #pragma unroll
    for (int j = 0; j < 6; ++j) w0v[j] = A.w[0][o + j];
    b0a = A.bs[0][r * 1024 + 2 * node512];
    b0b = A.bs[0][r * 1024 + 2 * node512 + 1];
  }
  // level 1 (1024->512): lane owns node512
  float w1a, w1b, b1v;
  {
    const int n = r * 512 + node512;
    w1a = A.w[1][n * 2 + 0];
    w1b = A.w[1][n * 2 + 1];
    b1v = A.bs[1][n];
  }
  // levels 2..7: xor-butterfly steps s=0..5 (stride 1<<s).
  // Before step s, lane l holds node c*(64>>s) + (l>>s) of level K=512>>s.
  // Swapped-weight trick: wso multiplies OWN value, wst multiplies partner's.
  float wso[6], wst[6], bsv[6];
  #pragma unroll
  for (int s = 0; s < 6; ++s) {
    const int mo  = c * (32 >> s) + (l >> (s + 1));   // output node within r
    const int idx = r * (256 >> s) + mo;
    const int odd = (l >> s) & 1;                     // own value is odd child?
    wso[s] = A.w[2 + s][idx * 2 + odd];
    wst[s] = A.w[2 + s][idx * 2 + (odd ^ 1)];
    bsv[s] = A.bs[2 + s][idx];
  }

  __shared__ float lds_buf[BPB][2][8];
  const int bbase = blockIdx.x * BPB;

  for (int bi = 0; bi < BPB; bi += ROWS) {
    float v[ROWS];
    #pragma unroll
    for (int u = 0; u < ROWS; ++u) {
      const int b = bbase + bi + u;
      const float2* xp = reinterpret_cast<const float2*>(A.x + (size_t)b * K0 + kb);
      const float2 xa = xp[0], xb = xp[1], xc = xp[2];
      const float xv[6] = {xa.x, xa.y, xb.x, xb.y, xc.x, xc.y};

      float acc0 = b0a, acc1 = b0b;
      #pragma unroll
      for (int j = 0; j < 6; ++j) {
        float tp = fmaf(p1l[j], xv[j], p2l[j]);
        float tm = fmaf(m1l[j], xv[j], m2l[j]);
        tp = fminf(fmaxf(tp, -CL), CL);
        tm = fminf(fmaxf(tm, -CL), CL);
        const float gp = __builtin_amdgcn_exp2f(tp);
        const float gm = __builtin_amdgcn_exp2f(tm);
        const float num = fmaf(50.0f, gp, fmaf(-70.0f, gm, z65[j]));
        const float den = gp + gm + z0v[j];
        float rr = __builtin_amdgcn_rcpf(den);
        rr = rr * fmaf(-den, rr, 2.0f);          // Newton: ~0.5 ulp
        const float s = num * rr;
        if (j < 3) acc0 = fmaf(w0v[j], s, acc0);
        else       acc1 = fmaf(w0v[j], s, acc1);
      }
      acc0 = lrelu(acc0);
      acc1 = lrelu(acc1);
      v[u] = lrelu(fmaf(w1a, acc0, fmaf(w1b, acc1, b1v)));
    }

    // butterfly tree: 2 rows interleaved per step to hide shuffle latency
    #pragma unroll
    for (int s = 0; s < 6; ++s) {
      float pv[ROWS];
      #pragma unroll
      for (int u = 0; u < ROWS; ++u) pv[u] = __shfl_xor(v[u], 1 << s, 64);
      #pragma unroll
      for (int u = 0; u < ROWS; ++u)
        v[u] = lrelu(fmaf(wso[s], v[u], fmaf(wst[s], pv[u], bsv[s])));
    }
    if (l == 0) {
      #pragma unroll
      for (int u = 0; u < ROWS; ++u) lds_buf[bi + u][r][c] = v[u];
    }
  }
  __syncthreads();

  // finisher: levels 8..10 + root, one thread per batch row (fp32)
  if (tid < BPB) {
    const int b = bbase + tid;
    float o = A.root_b[0];
    #pragma unroll
    for (int rr = 0; rr < 2; ++rr) {
      float v8[8];
      #pragma unroll
      for (int q = 0; q < 8; ++q) v8[q] = lds_buf[tid][rr][q];
      float v4[4];
      #pragma unroll
      for (int n = 0; n < 4; ++n)
        v4[n] = lrelu(fmaf(A.w[8][(rr * 4 + n) * 2 + 0], v8[2 * n],
                      fmaf(A.w[8][(rr * 4 + n) * 2 + 1], v8[2 * n + 1],
                           A.bs[8][rr * 4 + n])));
      float v2[2];
      #pragma unroll
      for (int n = 0; n < 2; ++n)
        v2[n] = lrelu(fmaf(A.w[9][(rr * 2 + n) * 2 + 0], v4[2 * n],
                      fmaf(A.w[9][(rr * 2 + n) * 2 + 1], v4[2 * n + 1],
                           A.bs[9][rr * 2 + n])));
      const float v1 = lrelu(fmaf(A.w[10][rr * 2 + 0], v2[0],
                             fmaf(A.w[10][rr * 2 + 1], v2[1],
                                  A.bs[10][rr])));
      o = fmaf(A.root_w[rr], v1, o);
    }
    A.out[b] = o;
  }
}

extern "C" void kernel_launch(void* const* d_in, const int* in_sizes, int n_in,
                              void* d_out, int out_size, void* d_ws, size_t ws_size,
                              hipStream_t stream) {
  KtreeArgs A;
  A.x   = (const float*)d_in[0];
  A.ap1 = (const float*)d_in[1];
  A.ap2 = (const float*)d_in[2];
  A.am1 = (const float*)d_in[3];
  A.am2 = (const float*)d_in[4];
  A.g0  = (const float*)d_in[5];
  for (int i = 0; i < 11; ++i) {
    A.w[i]  = (const float*)d_in[6 + 2 * i];
    A.bs[i] = (const float*)d_in[7 + 2 * i];
  }
  A.root_w = (const float*)d_in[28];
  A.root_b = (const float*)d_in[29];
  A.out = (float*)d_out;

  const int grid = 8192 / BPB;   // 256 blocks x 1024 threads
  hipLaunchKernelGGL(ktree_synapse_kernel, dim3(grid), dim3(BLOCK), 0, stream, A);
}